// Round 1
// baseline (398.864 us; speedup 1.0000x reference)
//
#include <hip/hip_runtime.h>
#include <hip/hip_bf16.h>

// Problem constants (B,N,D,H from reference)
#define Bc 64
#define Nc 512
#define Dc 1024
#define Hc 2048
#define Mc (Bc * Nc)          // 32768 rows

// GEMM tiling
#define BM 128
#define BH 128
#define BK 64
#define KTILES (Dc / BK)      // 16
#define HGROUPS 4
#define HT_PER_GROUP (Hc / BH / HGROUPS)  // 4
#define NSLICE 8              // HGROUPS * 2 wave-columns

typedef __attribute__((ext_vector_type(8))) short bf16x8;
typedef __attribute__((ext_vector_type(4))) float f32x4;

__device__ __forceinline__ unsigned short f2bf(float f) {
    unsigned u = __float_as_uint(f);
    u += 0x7FFFu + ((u >> 16) & 1u);   // RNE
    return (unsigned short)(u >> 16);
}

__device__ __forceinline__ void stage16(const void* g, void* l) {
    __builtin_amdgcn_global_load_lds(
        (const __attribute__((address_space(1))) unsigned int*)g,
        (__attribute__((address_space(3))) unsigned int*)l,
        16, 0, 0);
}

// ---------------- Kernel A: cast x -> bf16, energy = sigmoid(rowsum(x^2)) ----
__global__ void __launch_bounds__(256) cast_energy(
    const float* __restrict__ x, unsigned short* __restrict__ xb,
    float* __restrict__ energy)
{
    const int row = blockIdx.x;            // 0..Mc-1
    const int tid = threadIdx.x;           // 256 threads, 4 f32 each
    const float4 v = ((const float4*)(x + (size_t)row * Dc))[tid];
    ushort4 o;
    o.x = f2bf(v.x); o.y = f2bf(v.y); o.z = f2bf(v.z); o.w = f2bf(v.w);
    ((ushort4*)(xb + (size_t)row * Dc))[tid] = o;

    float s = v.x * v.x + v.y * v.y + v.z * v.z + v.w * v.w;
    #pragma unroll
    for (int m = 1; m < 64; m <<= 1) s += __shfl_xor(s, m);
    __shared__ float ws[4];
    if ((tid & 63) == 0) ws[tid >> 6] = s;
    __syncthreads();
    if (tid == 0) {
        float t = ws[0] + ws[1] + ws[2] + ws[3];
        energy[row] = 1.0f / (1.0f + expf(-t));
    }
}

// ---------------- Kernel B: cast W1 -> bf16 ---------------------------------
__global__ void __launch_bounds__(256) cast_w1(
    const float* __restrict__ w1, unsigned short* __restrict__ w1b)
{
    const size_t i = (size_t)blockIdx.x * blockDim.x + threadIdx.x; // x4 elems
    const float4 v = ((const float4*)w1)[i];
    ushort4 o;
    o.x = f2bf(v.x); o.y = f2bf(v.y); o.z = f2bf(v.z); o.w = f2bf(v.w);
    ((ushort4*)w1b)[i] = o;
}

// ---------------- Kernel C: fused bf16 GEMM + relu + W2-reduce --------------
// score_part[(hg*2 + wc) * Mc + row] = sum over this slice's h of
//     relu(x.W1[h] + b1[h]) * W2[h]
__global__ void __launch_bounds__(256) fused_gemm_score(
    const unsigned short* __restrict__ xb,    // [Mc][Dc] bf16 bits
    const unsigned short* __restrict__ w1b,   // [Hc][Dc] bf16 bits
    const float* __restrict__ b1,             // [Hc]
    const float* __restrict__ w2,             // [Hc]
    float* __restrict__ score_part)           // [NSLICE][Mc]
{
    __shared__ unsigned short sA[BM][BK];     // 16 KB
    __shared__ unsigned short sB[BH][BK];     // 16 KB

    const int tid  = threadIdx.x;
    const int lane = tid & 63;
    const int wave = tid >> 6;                // 0..3
    const int wr   = wave >> 1;               // row half of tile
    const int wc   = wave & 1;                // col half of tile
    const int l15  = lane & 15;
    const int l4   = lane >> 4;               // 0..3

    const int m0 = blockIdx.x * BM;           // 256 m-tiles
    const int hg = blockIdx.y;                // 0..3

    // staging geometry: chunk = 256 thr x 16B = 32 rows of 64 bf16
    const int srow = tid >> 3;                // 0..31
    const int scol = (tid & 7) * 8;           // bf16 col

    float sp[4][4];                           // per-lane score partials [m][j]
    #pragma unroll
    for (int m = 0; m < 4; ++m)
        #pragma unroll
        for (int j = 0; j < 4; ++j) sp[m][j] = 0.0f;

    for (int ht = 0; ht < HT_PER_GROUP; ++ht) {
        const int h0 = (hg * HT_PER_GROUP + ht) * BH;

        f32x4 acc[4][4];
        #pragma unroll
        for (int m = 0; m < 4; ++m)
            #pragma unroll
            for (int n = 0; n < 4; ++n) acc[m][n] = (f32x4)(0.0f);

        for (int kt = 0; kt < KTILES; ++kt) {
            const int k0 = kt * BK;
            #pragma unroll
            for (int c = 0; c < 4; ++c) {
                const unsigned short* gA =
                    xb + (size_t)(m0 + c * 32 + srow) * Dc + k0 + scol;
                stage16(gA, ((char*)&sA[0][0]) + c * 4096 + wave * 1024);
                const unsigned short* gB =
                    w1b + (size_t)(h0 + c * 32 + srow) * Dc + k0 + scol;
                stage16(gB, ((char*)&sB[0][0]) + c * 4096 + wave * 1024);
            }
            __syncthreads();
            #pragma unroll
            for (int ks = 0; ks < 2; ++ks) {
                bf16x8 af[4], bfr[4];
                #pragma unroll
                for (int m = 0; m < 4; ++m)
                    af[m] = *(const bf16x8*)&sA[wr * 64 + m * 16 + l15][ks * 32 + l4 * 8];
                #pragma unroll
                for (int n = 0; n < 4; ++n)
                    bfr[n] = *(const bf16x8*)&sB[wc * 64 + n * 16 + l15][ks * 32 + l4 * 8];
                #pragma unroll
                for (int m = 0; m < 4; ++m)
                    #pragma unroll
                    for (int n = 0; n < 4; ++n)
                        acc[m][n] = __builtin_amdgcn_mfma_f32_16x16x32_bf16(
                            af[m], bfr[n], acc[m][n], 0, 0, 0);
            }
            __syncthreads();
        }

        // fold this h-tile: +b1, relu, *W2, accumulate per-row partials
        #pragma unroll
        for (int n = 0; n < 4; ++n) {
            const int h = h0 + wc * 64 + n * 16 + l15;
            const float b1v = b1[h];
            const float w2v = w2[h];
            #pragma unroll
            for (int m = 0; m < 4; ++m)
                #pragma unroll
                for (int j = 0; j < 4; ++j) {
                    float v = acc[m][n][j] + b1v;
                    v = v > 0.0f ? v : 0.0f;
                    sp[m][j] += v * w2v;
                }
        }
    }

    // reduce over the 16 h-columns held by lanes (bits 0..3 of lane)
    #pragma unroll
    for (int m = 0; m < 4; ++m)
        #pragma unroll
        for (int j = 0; j < 4; ++j) {
            float v = sp[m][j];
            v += __shfl_xor(v, 1);
            v += __shfl_xor(v, 2);
            v += __shfl_xor(v, 4);
            v += __shfl_xor(v, 8);
            sp[m][j] = v;
        }

    if (l15 == 0) {
        const size_t base = (size_t)(hg * 2 + wc) * Mc;
        #pragma unroll
        for (int m = 0; m < 4; ++m)
            #pragma unroll
            for (int j = 0; j < 4; ++j) {
                const int row = m0 + wr * 64 + m * 16 + l4 * 4 + j;
                score_part[base + row] = sp[m][j];
            }
    }
}

// ---------------- Kernel D: finalize + write filter matrix ------------------
__global__ void __launch_bounds__(256) finalize(
    const float* __restrict__ score_part, const float* __restrict__ energy,
    const float* __restrict__ b2, float* __restrict__ out)
{
    const int row = blockIdx.x * 2 + (threadIdx.x >> 7);  // 0..Mc-1
    const int t   = threadIdx.x & 127;                    // 128 thr per row

    float s = b2[0];
    #pragma unroll
    for (int g = 0; g < NSLICE; ++g) s += score_part[(size_t)g * Mc + row];
    const float attn = (1.0f / (1.0f + expf(-s))) * energy[row];

    const int n = row & (Nc - 1);
    float4 z = make_float4(0.0f, 0.0f, 0.0f, 0.0f);
    if (t == (n >> 2)) ((float*)&z)[n & 3] = attn;
    ((float4*)(out + (size_t)row * Nc))[t] = z;
    if (t == 0) out[(size_t)Bc * Nc * Nc + row] = attn;
}

// ---------------- Host launcher ---------------------------------------------
extern "C" void kernel_launch(void* const* d_in, const int* in_sizes, int n_in,
                              void* d_out, int out_size, void* d_ws, size_t ws_size,
                              hipStream_t stream) {
    const float* x  = (const float*)d_in[0];
    const float* W1 = (const float*)d_in[1];
    const float* b1 = (const float*)d_in[2];
    const float* W2 = (const float*)d_in[3];
    const float* b2 = (const float*)d_in[4];
    float* out = (float*)d_out;

    const size_t xb_bytes = (size_t)Mc * Dc * 2;   // 64 MB
    const size_t w1_bytes = (size_t)Hc * Dc * 2;   // 4 MB
    const size_t e_bytes  = (size_t)Mc * 4;        // 128 KB
    const size_t s_bytes  = (size_t)NSLICE * Mc * 4; // 1 MB

    char* ws = (char*)d_ws;
    unsigned short* xb;
    if (ws_size >= xb_bytes + w1_bytes + e_bytes + s_bytes + 256) {
        xb = (unsigned short*)ws; ws += xb_bytes;
    } else {
        // use the filter region of d_out (67 MB >= 64 MB) as bf16-x scratch;
        // finalize() fully overwrites it afterwards.
        xb = (unsigned short*)d_out;
    }
    unsigned short* w1b = (unsigned short*)ws; ws += w1_bytes;
    float* energy = (float*)ws; ws += e_bytes;
    float* score  = (float*)ws; ws += s_bytes;

    cast_energy<<<Mc, 256, 0, stream>>>(x, xb, energy);
    cast_w1<<<(Hc * Dc / 4) / 256, 256, 0, stream>>>(W1, w1b);
    fused_gemm_score<<<dim3(Mc / BM, HGROUPS), 256, 0, stream>>>(xb, w1b, b1, W2, score);
    finalize<<<Mc / 2, 256, 0, stream>>>(score, energy, b2, out);
}

// Round 2
// 284.495 us; speedup vs baseline: 1.4020x; 1.4020x over previous
//
#include <hip/hip_runtime.h>
#include <hip/hip_bf16.h>

// Problem constants (B,N,D,H from reference)
#define Bc 64
#define Nc 512
#define Dc 1024
#define Hc 2048
#define Mc (Bc * Nc)          // 32768 rows

// GEMM tiling
#define BM 128
#define BH 128
#define BK 64
#define KTILES (Dc / BK)      // 16
#define MTILES (Mc / BM)      // 256
#define HTILES (Hc / BH)      // 16
#define NSLICE (HTILES * 2)   // 32 score slices (ht x wave-column)

typedef __attribute__((ext_vector_type(8))) short bf16x8;
typedef __attribute__((ext_vector_type(4))) float f32x4;

__device__ __forceinline__ unsigned short f2bf(float f) {
    unsigned u = __float_as_uint(f);
    u += 0x7FFFu + ((u >> 16) & 1u);   // RNE
    return (unsigned short)(u >> 16);
}

__device__ __forceinline__ void stage16(const void* g, void* l) {
    __builtin_amdgcn_global_load_lds(
        (const __attribute__((address_space(1))) unsigned int*)g,
        (__attribute__((address_space(3))) unsigned int*)l,
        16, 0, 0);
}

// ---------------- Kernel A: cast x -> bf16, energy = sigmoid(rowsum(x^2)) ----
__global__ void __launch_bounds__(256) cast_energy(
    const float* __restrict__ x, unsigned short* __restrict__ xb,
    float* __restrict__ energy)
{
    const int row = blockIdx.x;            // 0..Mc-1
    const int tid = threadIdx.x;           // 256 threads, 4 f32 each
    const float4 v = ((const float4*)(x + (size_t)row * Dc))[tid];
    ushort4 o;
    o.x = f2bf(v.x); o.y = f2bf(v.y); o.z = f2bf(v.z); o.w = f2bf(v.w);
    ((ushort4*)(xb + (size_t)row * Dc))[tid] = o;

    float s = v.x * v.x + v.y * v.y + v.z * v.z + v.w * v.w;
    #pragma unroll
    for (int m = 1; m < 64; m <<= 1) s += __shfl_xor(s, m);
    __shared__ float ws[4];
    if ((tid & 63) == 0) ws[tid >> 6] = s;
    __syncthreads();
    if (tid == 0) {
        float t = ws[0] + ws[1] + ws[2] + ws[3];
        energy[row] = 1.0f / (1.0f + expf(-t));
    }
}

// ---------------- Kernel B: cast W1 -> bf16 ---------------------------------
__global__ void __launch_bounds__(256) cast_w1(
    const float* __restrict__ w1, unsigned short* __restrict__ w1b)
{
    const size_t i = (size_t)blockIdx.x * blockDim.x + threadIdx.x; // x4 elems
    const float4 v = ((const float4*)w1)[i];
    ushort4 o;
    o.x = f2bf(v.x); o.y = f2bf(v.y); o.z = f2bf(v.z); o.w = f2bf(v.w);
    ((ushort4*)w1b)[i] = o;
}

// ---------------- Kernel C: fused bf16 GEMM + relu + W2-reduce --------------
// One (m-tile, h-tile) per block. score_part[(ht*2 + wc)*Mc + row] =
//   sum over this slice's 64 h of relu(x.W1[h] + b1[h]) * W2[h]
__global__ void __launch_bounds__(256) fused_gemm_score(
    const unsigned short* __restrict__ xb,    // [Mc][Dc] bf16 bits
    const unsigned short* __restrict__ w1b,   // [Hc][Dc] bf16 bits
    const float* __restrict__ b1,             // [Hc]
    const float* __restrict__ w2,             // [Hc]
    float* __restrict__ score_part)           // [NSLICE][Mc]
{
    __shared__ unsigned short sA[BM][BK];     // 16 KB
    __shared__ unsigned short sB[BH][BK];     // 16 KB

    const int tid  = threadIdx.x;
    const int lane = tid & 63;
    const int wave = tid >> 6;                // 0..3
    const int wr   = wave >> 1;               // row half of tile
    const int wc   = wave & 1;                // col half of tile
    const int l15  = lane & 15;
    const int l4   = lane >> 4;               // 0..3

    // chunked XCD swizzle: 4096 blocks % 8 == 0 -> bijective simple form.
    // Within an XCD, consecutive wg share the same m-tile (ht fastest) so the
    // 16 blocks reading one x-tile run adjacently and hit that XCD's L2.
    const int b  = blockIdx.x;
    const int wg = (b & 7) * (MTILES * HTILES / 8) + (b >> 3);
    const int mt = wg >> 4;                   // 0..255
    const int ht = wg & 15;                   // 0..15
    const int m0 = mt * BM;
    const int h0 = ht * BH;

    // prefetch epilogue coefficients (issued before the K-loop; consumed after)
    float b1v[4], w2v[4];
    #pragma unroll
    for (int n = 0; n < 4; ++n) {
        const int h = h0 + wc * 64 + n * 16 + l15;
        b1v[n] = b1[h];
        w2v[n] = w2[h];
    }

    // staging geometry: chunk = 256 thr x 16B = 32 rows of 64 bf16
    const int srow = tid >> 3;                // 0..31
    const int scol = (tid & 7) * 8;           // bf16 col

    f32x4 acc[4][4];
    #pragma unroll
    for (int m = 0; m < 4; ++m)
        #pragma unroll
        for (int n = 0; n < 4; ++n) acc[m][n] = (f32x4)(0.0f);

    for (int kt = 0; kt < KTILES; ++kt) {
        const int k0 = kt * BK;
        #pragma unroll
        for (int c = 0; c < 4; ++c) {
            const unsigned short* gA =
                xb + (size_t)(m0 + c * 32 + srow) * Dc + k0 + scol;
            stage16(gA, ((char*)&sA[0][0]) + c * 4096 + wave * 1024);
            const unsigned short* gB =
                w1b + (size_t)(h0 + c * 32 + srow) * Dc + k0 + scol;
            stage16(gB, ((char*)&sB[0][0]) + c * 4096 + wave * 1024);
        }
        __syncthreads();
        #pragma unroll
        for (int ks = 0; ks < 2; ++ks) {
            bf16x8 af[4], bfr[4];
            #pragma unroll
            for (int m = 0; m < 4; ++m)
                af[m] = *(const bf16x8*)&sA[wr * 64 + m * 16 + l15][ks * 32 + l4 * 8];
            #pragma unroll
            for (int n = 0; n < 4; ++n)
                bfr[n] = *(const bf16x8*)&sB[wc * 64 + n * 16 + l15][ks * 32 + l4 * 8];
            #pragma unroll
            for (int m = 0; m < 4; ++m)
                #pragma unroll
                for (int n = 0; n < 4; ++n)
                    acc[m][n] = __builtin_amdgcn_mfma_f32_16x16x32_bf16(
                        af[m], bfr[n], acc[m][n], 0, 0, 0);
        }
        __syncthreads();
    }

    // fold: +b1, relu, *W2 -> per-row partials
    float sp[4][4];
    #pragma unroll
    for (int m = 0; m < 4; ++m)
        #pragma unroll
        for (int j = 0; j < 4; ++j) sp[m][j] = 0.0f;
    #pragma unroll
    for (int n = 0; n < 4; ++n)
        #pragma unroll
        for (int m = 0; m < 4; ++m)
            #pragma unroll
            for (int j = 0; j < 4; ++j) {
                float v = acc[m][n][j] + b1v[n];
                v = v > 0.0f ? v : 0.0f;
                sp[m][j] += v * w2v[n];
            }

    // reduce over the 16 h-columns held by lanes (bits 0..3 of lane)
    #pragma unroll
    for (int m = 0; m < 4; ++m)
        #pragma unroll
        for (int j = 0; j < 4; ++j) {
            float v = sp[m][j];
            v += __shfl_xor(v, 1);
            v += __shfl_xor(v, 2);
            v += __shfl_xor(v, 4);
            v += __shfl_xor(v, 8);
            sp[m][j] = v;
        }

    if (l15 == 0) {
        const size_t base = (size_t)(ht * 2 + wc) * Mc;
        #pragma unroll
        for (int m = 0; m < 4; ++m)
            #pragma unroll
            for (int j = 0; j < 4; ++j) {
                const int row = m0 + wr * 64 + m * 16 + l4 * 4 + j;
                score_part[base + row] = sp[m][j];
            }
    }
}

// ---------------- Kernel D: finalize + write filter matrix ------------------
__global__ void __launch_bounds__(256) finalize(
    const float* __restrict__ score_part, const float* __restrict__ energy,
    const float* __restrict__ b2, float* __restrict__ out)
{
    const int row = blockIdx.x * 2 + (threadIdx.x >> 7);  // 0..Mc-1
    const int t   = threadIdx.x & 127;                    // 128 thr per row

    float s = b2[0];
    #pragma unroll
    for (int g = 0; g < NSLICE; ++g) s += score_part[(size_t)g * Mc + row];
    const float attn = (1.0f / (1.0f + expf(-s))) * energy[row];

    const int n = row & (Nc - 1);
    float4 z = make_float4(0.0f, 0.0f, 0.0f, 0.0f);
    if (t == (n >> 2)) ((float*)&z)[n & 3] = attn;
    ((float4*)(out + (size_t)row * Nc))[t] = z;
    if (t == 0) out[(size_t)Bc * Nc * Nc + row] = attn;
}

// ---------------- Host launcher ---------------------------------------------
extern "C" void kernel_launch(void* const* d_in, const int* in_sizes, int n_in,
                              void* d_out, int out_size, void* d_ws, size_t ws_size,
                              hipStream_t stream) {
    const float* x  = (const float*)d_in[0];
    const float* W1 = (const float*)d_in[1];
    const float* b1 = (const float*)d_in[2];
    const float* W2 = (const float*)d_in[3];
    const float* b2 = (const float*)d_in[4];
    float* out = (float*)d_out;

    const size_t xb_bytes = (size_t)Mc * Dc * 2;     // 64 MB
    const size_t w1_bytes = (size_t)Hc * Dc * 2;     // 4 MB
    const size_t e_bytes  = (size_t)Mc * 4;          // 128 KB
    const size_t s_bytes  = (size_t)NSLICE * Mc * 4; // 4 MB

    char* ws = (char*)d_ws;
    unsigned short* xb;
    if (ws_size >= xb_bytes + w1_bytes + e_bytes + s_bytes + 256) {
        xb = (unsigned short*)ws; ws += xb_bytes;
    } else {
        // use the filter region of d_out (67 MB >= 64 MB) as bf16-x scratch;
        // finalize() fully overwrites it afterwards.
        xb = (unsigned short*)d_out;
    }
    unsigned short* w1b = (unsigned short*)ws; ws += w1_bytes;
    float* energy = (float*)ws; ws += e_bytes;
    float* score  = (float*)ws; ws += s_bytes;

    cast_energy<<<Mc, 256, 0, stream>>>(x, xb, energy);
    cast_w1<<<(Hc * Dc / 4) / 256, 256, 0, stream>>>(W1, w1b);
    fused_gemm_score<<<MTILES * HTILES, 256, 0, stream>>>(xb, w1b, b1, W2, score);
    finalize<<<Mc / 2, 256, 0, stream>>>(score, energy, b2, out);
}

// Round 3
// 206.457 us; speedup vs baseline: 1.9319x; 1.3780x over previous
//
#include <hip/hip_runtime.h>
#include <hip/hip_bf16.h>

// Problem constants (B,N,D,H from reference)
#define Bc 64
#define Nc 512
#define Dc 1024
#define Hc 2048
#define Mc (Bc * Nc)          // 32768 rows

// GEMM tiling: 256x256 tile, BK=64, 8 waves (2M x 4N), double-buffered LDS
#define BM 256
#define BH 256
#define BK 64
#define KTILES (Dc / BK)      // 16
#define MTILES (Mc / BM)      // 128
#define HTILES (Hc / BH)      // 8
#define NSLICE (HTILES * 4)   // 32 score slices (ht x wave-column)

typedef __attribute__((ext_vector_type(8))) short bf16x8;
typedef __attribute__((ext_vector_type(4))) float f32x4;

__device__ __forceinline__ unsigned short f2bf(float f) {
    unsigned u = __float_as_uint(f);
    u += 0x7FFFu + ((u >> 16) & 1u);   // RNE
    return (unsigned short)(u >> 16);
}

__device__ __forceinline__ void stage16(const void* g, void* l) {
    __builtin_amdgcn_global_load_lds(
        (const __attribute__((address_space(1))) unsigned int*)g,
        (__attribute__((address_space(3))) unsigned int*)l,
        16, 0, 0);
}

// ---------------- Kernel A: cast x -> bf16, energy = sigmoid(rowsum(x^2)) ----
__global__ void __launch_bounds__(256) cast_energy(
    const float* __restrict__ x, unsigned short* __restrict__ xb,
    float* __restrict__ energy)
{
    const int row = blockIdx.x;            // 0..Mc-1
    const int tid = threadIdx.x;           // 256 threads, 4 f32 each
    const float4 v = ((const float4*)(x + (size_t)row * Dc))[tid];
    ushort4 o;
    o.x = f2bf(v.x); o.y = f2bf(v.y); o.z = f2bf(v.z); o.w = f2bf(v.w);
    ((ushort4*)(xb + (size_t)row * Dc))[tid] = o;

    float s = v.x * v.x + v.y * v.y + v.z * v.z + v.w * v.w;
    #pragma unroll
    for (int m = 1; m < 64; m <<= 1) s += __shfl_xor(s, m);
    __shared__ float ws[4];
    if ((tid & 63) == 0) ws[tid >> 6] = s;
    __syncthreads();
    if (tid == 0) {
        float t = ws[0] + ws[1] + ws[2] + ws[3];
        energy[row] = 1.0f / (1.0f + expf(-t));
    }
}

// ---------------- Kernel B: cast W1 -> bf16 ---------------------------------
__global__ void __launch_bounds__(256) cast_w1(
    const float* __restrict__ w1, unsigned short* __restrict__ w1b)
{
    const size_t i = (size_t)blockIdx.x * blockDim.x + threadIdx.x; // x4 elems
    const float4 v = ((const float4*)w1)[i];
    ushort4 o;
    o.x = f2bf(v.x); o.y = f2bf(v.y); o.z = f2bf(v.z); o.w = f2bf(v.w);
    ((ushort4*)w1b)[i] = o;
}

// ---------------- Kernel C: fused bf16 GEMM + relu + W2-reduce --------------
// 256x256 tile per block, 8 waves, double-buffered LDS with prefetch-1.
// score_part[(ht*4 + wc)*Mc + row] = sum over slice's 64 h of
//     relu(x.W1[h] + b1[h]) * W2[h]
__global__ void __launch_bounds__(512, 2) fused_gemm_score(
    const unsigned short* __restrict__ xb,    // [Mc][Dc] bf16 bits
    const unsigned short* __restrict__ w1b,   // [Hc][Dc] bf16 bits
    const float* __restrict__ b1,             // [Hc]
    const float* __restrict__ w2,             // [Hc]
    float* __restrict__ score_part)           // [NSLICE][Mc]
{
    // dynamic LDS: [2 buf][2 mat][256*64] bf16 = 128 KB
    extern __shared__ unsigned short lds[];

    const int tid  = threadIdx.x;
    const int lane = tid & 63;
    const int wid  = tid >> 6;                // 0..7
    const int wr   = wid >> 2;                // 0..1  (m half: 128 rows)
    const int wc   = wid & 3;                 // 0..3  (h quarter: 64 cols)
    const int l15  = lane & 15;
    const int l4   = lane >> 4;               // 0..3

    // bijective XCD swizzle (1024 % 8 == 0): ht fastest within an XCD so the
    // 8 blocks sharing one x-tile run adjacently; W1 (4MB) stays L2-resident.
    const int b  = blockIdx.x;
    const int wg = (b & 7) * (MTILES * HTILES / 8) + (b >> 3);
    const int mt = wg >> 3;                   // 0..127
    const int ht = wg & 7;                    // 0..7
    const int m0 = mt * BM;
    const int h0 = ht * BH;

    // epilogue coefficients prefetch
    float b1v[4], w2v[4];
    #pragma unroll
    for (int n = 0; n < 4; ++n) {
        const int h = h0 + wc * 64 + n * 16 + l15;
        b1v[n] = b1[h];
        w2v[n] = w2[h];
    }

    // ---- staging geometry (rule #21: linear LDS dest + pre-swizzled src) ----
    // chunk = 512 thr x 16B = 8 KB = 64 rows of 128B. 4 chunks per matrix.
    // LDS linear byte (row*128 + (t&7)*16) holds logical colbyte
    // (t&7)*16 ^ ((row&7)<<4)  -> global src col is pre-swizzled.
    const int srow    = tid >> 3;             // 0..63
    const int scol_sw = ((((tid & 7) * 16) ^ ((srow & 7) << 4)) >> 1); // elems

    unsigned short* A0 = lds;                 // [buf*32768 + mat*16384]
    #define LDSBUF(buf, mat) (A0 + (buf) * 32768 + (mat) * 16384)

    // ds_read swizzle mask for fragment reads (row&7 == l15&7 for all frags)
    const int swz = (l15 & 7) << 4;

    f32x4 acc[8][4];
    #pragma unroll
    for (int m = 0; m < 8; ++m)
        #pragma unroll
        for (int n = 0; n < 4; ++n) acc[m][n] = (f32x4)(0.0f);

    // prologue: stage K-tile 0 into buf 0
    {
        const int k0 = 0;
        #pragma unroll
        for (int c = 0; c < 4; ++c) {
            stage16(xb  + (size_t)(m0 + c * 64 + srow) * Dc + k0 + scol_sw,
                    ((char*)LDSBUF(0, 0)) + c * 8192 + tid * 16);
            stage16(w1b + (size_t)(h0 + c * 64 + srow) * Dc + k0 + scol_sw,
                    ((char*)LDSBUF(0, 1)) + c * 8192 + tid * 16);
        }
    }
    __syncthreads();   // compiler drains vmcnt(0) here

    int cur = 0;
    for (int kt = 0; kt < KTILES; ++kt) {
        // issue next-tile staging FIRST: loads stay in flight across this
        // tile's entire compute; waited only at the end-of-tile barrier.
        if (kt + 1 < KTILES) {
            const int k0 = (kt + 1) * BK;
            const int nb = cur ^ 1;
            #pragma unroll
            for (int c = 0; c < 4; ++c) {
                stage16(xb  + (size_t)(m0 + c * 64 + srow) * Dc + k0 + scol_sw,
                        ((char*)LDSBUF(nb, 0)) + c * 8192 + tid * 16);
                stage16(w1b + (size_t)(h0 + c * 64 + srow) * Dc + k0 + scol_sw,
                        ((char*)LDSBUF(nb, 1)) + c * 8192 + tid * 16);
            }
        }

        const char* Ab = (const char*)LDSBUF(cur, 0);
        const char* Bb = (const char*)LDSBUF(cur, 1);

        // B fragments for the whole tile (8 x ds_read_b128, held in regs)
        bf16x8 bfrag[4][2];
        #pragma unroll
        for (int n = 0; n < 4; ++n)
            #pragma unroll
            for (int kk = 0; kk < 2; ++kk)
                bfrag[n][kk] = *(const bf16x8*)(Bb +
                    (wc * 64 + n * 16 + l15) * 128 + ((kk * 64 + l4 * 16) ^ swz));

        // 4 phases x (4 A-reads + 16 MFMA)
        #pragma unroll
        for (int mp = 0; mp < 4; ++mp) {
            bf16x8 afr[2][2];
            #pragma unroll
            for (int mm = 0; mm < 2; ++mm)
                #pragma unroll
                for (int kk = 0; kk < 2; ++kk)
                    afr[mm][kk] = *(const bf16x8*)(Ab +
                        (wr * 128 + (mp * 2 + mm) * 16 + l15) * 128 +
                        ((kk * 64 + l4 * 16) ^ swz));
            __builtin_amdgcn_s_setprio(1);
            #pragma unroll
            for (int mm = 0; mm < 2; ++mm)
                #pragma unroll
                for (int n = 0; n < 4; ++n)
                    #pragma unroll
                    for (int kk = 0; kk < 2; ++kk)
                        acc[mp * 2 + mm][n] = __builtin_amdgcn_mfma_f32_16x16x32_bf16(
                            afr[mm][kk], bfrag[n][kk], acc[mp * 2 + mm][n], 0, 0, 0);
            __builtin_amdgcn_s_setprio(0);
        }

        __syncthreads();   // vmcnt(0): next buffer staged; all reads of cur done
        cur ^= 1;
    }

    // fold: +b1, relu, *W2 -> per-row partials, then reduce over l15 columns
    float sp[8][4];
    #pragma unroll
    for (int m = 0; m < 8; ++m)
        #pragma unroll
        for (int j = 0; j < 4; ++j) sp[m][j] = 0.0f;
    #pragma unroll
    for (int n = 0; n < 4; ++n)
        #pragma unroll
        for (int m = 0; m < 8; ++m)
            #pragma unroll
            for (int j = 0; j < 4; ++j) {
                float v = acc[m][n][j] + b1v[n];
                v = v > 0.0f ? v : 0.0f;
                sp[m][j] += v * w2v[n];
            }

    #pragma unroll
    for (int m = 0; m < 8; ++m)
        #pragma unroll
        for (int j = 0; j < 4; ++j) {
            float v = sp[m][j];
            v += __shfl_xor(v, 1);
            v += __shfl_xor(v, 2);
            v += __shfl_xor(v, 4);
            v += __shfl_xor(v, 8);
            sp[m][j] = v;
        }

    if (l15 == 0) {
        const size_t base = (size_t)(ht * 4 + wc) * Mc;
        #pragma unroll
        for (int m = 0; m < 8; ++m)
            #pragma unroll
            for (int j = 0; j < 4; ++j) {
                const int row = m0 + wr * 128 + m * 16 + l4 * 4 + j;
                score_part[base + row] = sp[m][j];
            }
    }
}

// ---------------- Kernel D: finalize + write filter matrix ------------------
__global__ void __launch_bounds__(256) finalize(
    const float* __restrict__ score_part, const float* __restrict__ energy,
    const float* __restrict__ b2, float* __restrict__ out)
{
    const int row = blockIdx.x * 2 + (threadIdx.x >> 7);  // 0..Mc-1
    const int t   = threadIdx.x & 127;                    // 128 thr per row

    float s = b2[0];
    #pragma unroll
    for (int g = 0; g < NSLICE; ++g) s += score_part[(size_t)g * Mc + row];
    const float attn = (1.0f / (1.0f + expf(-s))) * energy[row];

    const int n = row & (Nc - 1);
    float4 z = make_float4(0.0f, 0.0f, 0.0f, 0.0f);
    if (t == (n >> 2)) ((float*)&z)[n & 3] = attn;
    ((float4*)(out + (size_t)row * Nc))[t] = z;
    if (t == 0) out[(size_t)Bc * Nc * Nc + row] = attn;
}

// ---------------- Host launcher ---------------------------------------------
extern "C" void kernel_launch(void* const* d_in, const int* in_sizes, int n_in,
                              void* d_out, int out_size, void* d_ws, size_t ws_size,
                              hipStream_t stream) {
    const float* x  = (const float*)d_in[0];
    const float* W1 = (const float*)d_in[1];
    const float* b1 = (const float*)d_in[2];
    const float* W2 = (const float*)d_in[3];
    const float* b2 = (const float*)d_in[4];
    float* out = (float*)d_out;

    const size_t xb_bytes = (size_t)Mc * Dc * 2;     // 64 MB
    const size_t w1_bytes = (size_t)Hc * Dc * 2;     // 4 MB
    const size_t e_bytes  = (size_t)Mc * 4;          // 128 KB
    const size_t s_bytes  = (size_t)NSLICE * Mc * 4; // 4 MB

    char* ws = (char*)d_ws;
    unsigned short* xb;
    if (ws_size >= xb_bytes + w1_bytes + e_bytes + s_bytes + 256) {
        xb = (unsigned short*)ws; ws += xb_bytes;
    } else {
        // use the filter region of d_out (67 MB >= 64 MB) as bf16-x scratch;
        // finalize() fully overwrites it afterwards.
        xb = (unsigned short*)d_out;
    }
    unsigned short* w1b = (unsigned short*)ws; ws += w1_bytes;
    float* energy = (float*)ws; ws += e_bytes;
    float* score  = (float*)ws; ws += s_bytes;

    cast_energy<<<Mc, 256, 0, stream>>>(x, xb, energy);
    cast_w1<<<(Hc * Dc / 4) / 256, 256, 0, stream>>>(W1, w1b);
    fused_gemm_score<<<MTILES * HTILES, 512, 131072, stream>>>(xb, w1b, b1, W2, score);
    finalize<<<Mc / 2, 256, 0, stream>>>(score, energy, b2, out);
}

// Round 4
// 205.775 us; speedup vs baseline: 1.9383x; 1.0033x over previous
//
#include <hip/hip_runtime.h>
#include <hip/hip_bf16.h>

// Problem constants (B,N,D,H from reference)
#define Bc 64
#define Nc 512
#define Dc 1024
#define Hc 2048
#define Mc (Bc * Nc)          // 32768 rows

// GEMM tiling: 256x256 tile, BK=64, 8 waves (2M x 4N), 8-phase dbuf schedule
#define BM 256
#define BH 256
#define BK 64
#define KTILES (Dc / BK)      // 16
#define MTILES (Mc / BM)      // 128
#define HTILES (Hc / BH)      // 8
#define NSLICE (HTILES * 4)   // 32 score slices (ht x wave-column)

typedef __attribute__((ext_vector_type(8))) short bf16x8;
typedef __attribute__((ext_vector_type(4))) float f32x4;

__device__ __forceinline__ unsigned short f2bf(float f) {
    unsigned u = __float_as_uint(f);
    u += 0x7FFFu + ((u >> 16) & 1u);   // RNE
    return (unsigned short)(u >> 16);
}

__device__ __forceinline__ void stage16(const void* g, void* l) {
    __builtin_amdgcn_global_load_lds(
        (const __attribute__((address_space(1))) unsigned int*)g,
        (__attribute__((address_space(3))) unsigned int*)l,
        16, 0, 0);
}

// ---------------- Kernel A: cast x -> bf16, energy = sigmoid(rowsum(x^2)) ----
__global__ void __launch_bounds__(256) cast_energy(
    const float* __restrict__ x, unsigned short* __restrict__ xb,
    float* __restrict__ energy)
{
    const int row = blockIdx.x;            // 0..Mc-1
    const int tid = threadIdx.x;           // 256 threads, 4 f32 each
    const float4 v = ((const float4*)(x + (size_t)row * Dc))[tid];
    ushort4 o;
    o.x = f2bf(v.x); o.y = f2bf(v.y); o.z = f2bf(v.z); o.w = f2bf(v.w);
    ((ushort4*)(xb + (size_t)row * Dc))[tid] = o;

    float s = v.x * v.x + v.y * v.y + v.z * v.z + v.w * v.w;
    #pragma unroll
    for (int m = 1; m < 64; m <<= 1) s += __shfl_xor(s, m);
    __shared__ float ws[4];
    if ((tid & 63) == 0) ws[tid >> 6] = s;
    __syncthreads();
    if (tid == 0) {
        float t = ws[0] + ws[1] + ws[2] + ws[3];
        energy[row] = 1.0f / (1.0f + expf(-t));
    }
}

// ---------------- Kernel B: cast W1 -> bf16 ---------------------------------
__global__ void __launch_bounds__(256) cast_w1(
    const float* __restrict__ w1, unsigned short* __restrict__ w1b)
{
    const size_t i = (size_t)blockIdx.x * blockDim.x + threadIdx.x; // x4 elems
    const float4 v = ((const float4*)w1)[i];
    ushort4 o;
    o.x = f2bf(v.x); o.y = f2bf(v.y); o.z = f2bf(v.z); o.w = f2bf(v.w);
    ((ushort4*)w1b)[i] = o;
}

// ---------------- Kernel C: fused bf16 GEMM + relu + W2-reduce --------------
// 256x256 tile per block, 8 waves, 8-phase double-buffered schedule with
// counted vmcnt (T3+T4), LDS XOR swizzle (T2), setprio (T5).
// Tile parity -> buffer: even K-tiles in buf0, odd in buf1.
// score_part[(ht*4 + wc)*Mc + row] = sum over slice's 64 h of
//     relu(x.W1[h] + b1[h]) * W2[h]
__global__ void __launch_bounds__(512, 2) fused_gemm_score(
    const unsigned short* __restrict__ xb,    // [Mc][Dc] bf16 bits
    const unsigned short* __restrict__ w1b,   // [Hc][Dc] bf16 bits
    const float* __restrict__ b1,             // [Hc]
    const float* __restrict__ w2,             // [Hc]
    float* __restrict__ score_part)           // [NSLICE][Mc]
{
    // [2 buf][A 32KB | B 32KB] = 128 KB dynamic LDS
    extern __shared__ __attribute__((aligned(16))) char lds[];

    const int tid  = threadIdx.x;
    const int lane = tid & 63;
    const int wid  = tid >> 6;                // 0..7
    const int wr   = wid >> 2;                // 0..1  (m half: 128 rows)
    const int wc   = wid & 3;                 // 0..3  (h quarter: 64 cols)
    const int l15  = lane & 15;
    const int l4   = lane >> 4;               // 0..3

    // bijective XCD swizzle (1024 % 8 == 0): ht fastest within an XCD.
    const int b  = blockIdx.x;
    const int wg = (b & 7) * (MTILES * HTILES / 8) + (b >> 3);
    const int mt = wg >> 3;                   // 0..127
    const int ht = wg & 7;                    // 0..7
    const int m0 = mt * BM;
    const int h0 = ht * BH;

    // epilogue coefficients prefetch
    float b1v[4], w2v[4];
    #pragma unroll
    for (int n = 0; n < 4; ++n) {
        const int h = h0 + wc * 64 + n * 16 + l15;
        b1v[n] = b1[h];
        w2v[n] = w2[h];
    }

    // staging geometry (rule #21: linear LDS dest + pre-swizzled src col)
    const int srow    = tid >> 3;             // 0..63
    const int scol_sw = ((((tid & 7) * 16) ^ ((srow & 7) << 4)) >> 1); // elems

    // swizzled ds_read offsets
    const int swz   = (l15 & 7) << 4;
    const int offk0 = ((l4 * 16) ^ swz);
    const int offk1 = ((64 + l4 * 16) ^ swz);
    const int arow  = (wr * 128 + l15) * 128; // byte row base within A
    const int brow  = (wc * 64 + l15) * 128;  // byte row base within B

#define LDSA(bf) (lds + (bf) * 65536)
#define LDSB(bf) (lds + (bf) * 65536 + 32768)

// stage one half-tile (2 x global_load_lds / thread); tile kt -> buf (kt&1)
#define STG_A(kt, h) { \
    const int _k = ((kt) & (KTILES - 1)) * BK; \
    char* _dst = LDSA((kt) & 1); \
    stage16(xb + (size_t)(m0 + (2*(h)) * 64 + srow) * Dc + _k + scol_sw, \
            _dst + (2*(h)) * 8192 + tid * 16); \
    stage16(xb + (size_t)(m0 + (2*(h)+1) * 64 + srow) * Dc + _k + scol_sw, \
            _dst + (2*(h)+1) * 8192 + tid * 16); }
#define STG_B(kt, h) { \
    const int _k = ((kt) & (KTILES - 1)) * BK; \
    char* _dst = LDSB((kt) & 1); \
    stage16(w1b + (size_t)(h0 + (2*(h)) * 64 + srow) * Dc + _k + scol_sw, \
            _dst + (2*(h)) * 8192 + tid * 16); \
    stage16(w1b + (size_t)(h0 + (2*(h)+1) * 64 + srow) * Dc + _k + scol_sw, \
            _dst + (2*(h)+1) * 8192 + tid * 16); }

// register sub-tile loads (all-static indices)
#define RD_A(bf, mh) { \
    _Pragma("unroll") for (int mf = 0; mf < 4; ++mf) { \
        pA[mf][0] = *(const bf16x8*)(LDSA(bf) + arow + ((mh)*64 + mf*16) * 128 + offk0); \
        pA[mf][1] = *(const bf16x8*)(LDSA(bf) + arow + ((mh)*64 + mf*16) * 128 + offk1); } }
#define RD_B(bf, nh) { \
    _Pragma("unroll") for (int nf = 0; nf < 2; ++nf) { \
        pB[nh][nf][0] = *(const bf16x8*)(LDSB(bf) + brow + ((nh)*32 + nf*16) * 128 + offk0); \
        pB[nh][nf][1] = *(const bf16x8*)(LDSB(bf) + brow + ((nh)*32 + nf*16) * 128 + offk1); } }

// one C-quadrant (m-half x n-half) x K=64 : 16 MFMA
#define MM(mh, nh) { \
    __builtin_amdgcn_s_setprio(1); \
    _Pragma("unroll") for (int mf = 0; mf < 4; ++mf) \
    _Pragma("unroll") for (int nf = 0; nf < 2; ++nf) { \
        acc[(mh)*4+mf][(nh)*2+nf] = __builtin_amdgcn_mfma_f32_16x16x32_bf16( \
            pA[mf][0], pB[nh][nf][0], acc[(mh)*4+mf][(nh)*2+nf], 0, 0, 0); \
        acc[(mh)*4+mf][(nh)*2+nf] = __builtin_amdgcn_mfma_f32_16x16x32_bf16( \
            pA[mf][1], pB[nh][nf][1], acc[(mh)*4+mf][(nh)*2+nf], 0, 0, 0); } \
    __builtin_amdgcn_s_setprio(0); }

#define BAR   __builtin_amdgcn_s_barrier()
#define LGKM0 { asm volatile("s_waitcnt lgkmcnt(0)" ::: "memory"); \
                __builtin_amdgcn_sched_barrier(0); }
#define VM6   asm volatile("s_waitcnt vmcnt(6)" ::: "memory")

    bf16x8 pA[4][2];        // current A m-half fragments
    bf16x8 pB[2][2][2];     // both B n-half fragments
    f32x4  acc[8][4];
    #pragma unroll
    for (int m = 0; m < 8; ++m)
        #pragma unroll
        for (int n = 0; n < 4; ++n) acc[m][n] = (f32x4)(0.0f);

    // prologue: tile0 fully (buf0), tile1 minus A1 (buf1); A1 lands in ph0.
    // issue order matters for vmcnt(6): newest 6 = t1.{B0,B1,A0}.
    STG_B(0, 0); STG_B(0, 1); STG_A(0, 0); STG_A(0, 1);
    STG_B(1, 0); STG_B(1, 1); STG_A(1, 0);
    VM6;
    BAR;

    for (int t = 0; t < KTILES / 2; ++t) {
        const int k1 = 2 * t + 1, k2 = 2 * t + 2, k3 = 2 * t + 3;
        // ph0: compute buf0 (m0 x n0); stage (2t+1).A1 -> buf1
        RD_A(0, 0); RD_B(0, 0); STG_A(k1, 1);
        BAR; LGKM0; MM(0, 0); BAR;
        // ph1: (m0 x n1)
        RD_B(0, 1);
        BAR; LGKM0; MM(0, 1); BAR;
        // ph2: (m1 x n0); stage k2.B0
        RD_A(0, 1); STG_B(k2, 0);
        BAR; LGKM0; MM(1, 0); BAR;
        // ph3: (m1 x n1); stage k2.B1 + k2.A0; counted wait for buf1 tile
        STG_B(k2, 1); STG_A(k2, 0);
        BAR; MM(1, 1); VM6; BAR;
        // ph4: compute buf1 (m0 x n0); stage k2.A1
        RD_A(1, 0); RD_B(1, 0); STG_A(k2, 1);
        BAR; LGKM0; MM(0, 0); BAR;
        // ph5: (m0 x n1)
        RD_B(1, 1);
        BAR; LGKM0; MM(0, 1); BAR;
        // ph6: (m1 x n0); stage k3.B0
        RD_A(1, 1); STG_B(k3, 0);
        BAR; LGKM0; MM(1, 0); BAR;
        // ph7: (m1 x n1); stage k3.B1 + k3.A0; counted wait for buf0 tile
        STG_B(k3, 1); STG_A(k3, 0);
        BAR; MM(1, 1); VM6; BAR;
    }

    // fold: +b1, relu, *W2 -> per-row partials, then reduce over l15 columns
    float sp[8][4];
    #pragma unroll
    for (int m = 0; m < 8; ++m)
        #pragma unroll
        for (int j = 0; j < 4; ++j) sp[m][j] = 0.0f;
    #pragma unroll
    for (int n = 0; n < 4; ++n)
        #pragma unroll
        for (int m = 0; m < 8; ++m)
            #pragma unroll
            for (int j = 0; j < 4; ++j) {
                float v = acc[m][n][j] + b1v[n];
                v = v > 0.0f ? v : 0.0f;
                sp[m][j] += v * w2v[n];
            }

    #pragma unroll
    for (int m = 0; m < 8; ++m)
        #pragma unroll
        for (int j = 0; j < 4; ++j) {
            float v = sp[m][j];
            v += __shfl_xor(v, 1);
            v += __shfl_xor(v, 2);
            v += __shfl_xor(v, 4);
            v += __shfl_xor(v, 8);
            sp[m][j] = v;
        }

    if (l15 == 0) {
        const size_t base = (size_t)(ht * 4 + wc) * Mc;
        #pragma unroll
        for (int m = 0; m < 8; ++m)
            #pragma unroll
            for (int j = 0; j < 4; ++j) {
                const int row = m0 + wr * 128 + m * 16 + l4 * 4 + j;
                score_part[base + row] = sp[m][j];
            }
    }
}

// ---------------- Kernel D: finalize + write filter matrix ------------------
__global__ void __launch_bounds__(256) finalize(
    const float* __restrict__ score_part, const float* __restrict__ energy,
    const float* __restrict__ b2, float* __restrict__ out)
{
    const int row = blockIdx.x * 2 + (threadIdx.x >> 7);  // 0..Mc-1
    const int t   = threadIdx.x & 127;                    // 128 thr per row

    float s = b2[0];
    #pragma unroll
    for (int g = 0; g < NSLICE; ++g) s += score_part[(size_t)g * Mc + row];
    const float attn = (1.0f / (1.0f + expf(-s))) * energy[row];

    const int n = row & (Nc - 1);
    float4 z = make_float4(0.0f, 0.0f, 0.0f, 0.0f);
    if (t == (n >> 2)) ((float*)&z)[n & 3] = attn;
    ((float4*)(out + (size_t)row * Nc))[t] = z;
    if (t == 0) out[(size_t)Bc * Nc * Nc + row] = attn;
}

// ---------------- Host launcher ---------------------------------------------
extern "C" void kernel_launch(void* const* d_in, const int* in_sizes, int n_in,
                              void* d_out, int out_size, void* d_ws, size_t ws_size,
                              hipStream_t stream) {
    const float* x  = (const float*)d_in[0];
    const float* W1 = (const float*)d_in[1];
    const float* b1 = (const float*)d_in[2];
    const float* W2 = (const float*)d_in[3];
    const float* b2 = (const float*)d_in[4];
    float* out = (float*)d_out;

    const size_t xb_bytes = (size_t)Mc * Dc * 2;     // 64 MB
    const size_t w1_bytes = (size_t)Hc * Dc * 2;     // 4 MB
    const size_t e_bytes  = (size_t)Mc * 4;          // 128 KB
    const size_t s_bytes  = (size_t)NSLICE * Mc * 4; // 4 MB

    char* ws = (char*)d_ws;
    unsigned short* xb;
    if (ws_size >= xb_bytes + w1_bytes + e_bytes + s_bytes + 256) {
        xb = (unsigned short*)ws; ws += xb_bytes;
    } else {
        // use the filter region of d_out (67 MB >= 64 MB) as bf16-x scratch;
        // finalize() fully overwrites it afterwards.
        xb = (unsigned short*)d_out;
    }
    unsigned short* w1b = (unsigned short*)ws; ws += w1_bytes;
    float* energy = (float*)ws; ws += e_bytes;
    float* score  = (float*)ws; ws += s_bytes;

    cast_energy<<<Mc, 256, 0, stream>>>(x, xb, energy);
    cast_w1<<<(Hc * Dc / 4) / 256, 256, 0, stream>>>(W1, w1b);
    fused_gemm_score<<<MTILES * HTILES, 512, 131072, stream>>>(xb, w1b, b1, W2, score);
    finalize<<<Mc / 2, 256, 0, stream>>>(score, energy, b2, out);
}

// Round 5
// 203.885 us; speedup vs baseline: 1.9563x; 1.0093x over previous
//
#include <hip/hip_runtime.h>
#include <hip/hip_bf16.h>

// Problem constants (B,N,D,H from reference)
#define Bc 64
#define Nc 512
#define Dc 1024
#define Hc 2048
#define Mc (Bc * Nc)          // 32768 rows

// GEMM tiling: 256x256 tile, BK=64, 8 waves (2M x 4N), double-buffered LDS
#define BM 256
#define BH 256
#define BK 64
#define KTILES (Dc / BK)      // 16
#define MTILES (Mc / BM)      // 128
#define HTILES (Hc / BH)      // 8
#define NSLICE (HTILES * 4)   // 32 score slices (ht x wave-column)

typedef __attribute__((ext_vector_type(8))) short bf16x8;
typedef __attribute__((ext_vector_type(4))) float f32x4;

__device__ __forceinline__ unsigned short f2bf(float f) {
    unsigned u = __float_as_uint(f);
    u += 0x7FFFu + ((u >> 16) & 1u);   // RNE
    return (unsigned short)(u >> 16);
}

__device__ __forceinline__ void stage16(const void* g, void* l) {
    __builtin_amdgcn_global_load_lds(
        (const __attribute__((address_space(1))) unsigned int*)g,
        (__attribute__((address_space(3))) unsigned int*)l,
        16, 0, 0);
}

// ---------------- Kernel A: cast x -> bf16, energy = sigmoid(rowsum(x^2)) ----
__global__ void __launch_bounds__(256) cast_energy(
    const float* __restrict__ x, unsigned short* __restrict__ xb,
    float* __restrict__ energy)
{
    const int row = blockIdx.x;            // 0..Mc-1
    const int tid = threadIdx.x;           // 256 threads, 4 f32 each
    const float4 v = ((const float4*)(x + (size_t)row * Dc))[tid];
    ushort4 o;
    o.x = f2bf(v.x); o.y = f2bf(v.y); o.z = f2bf(v.z); o.w = f2bf(v.w);
    ((ushort4*)(xb + (size_t)row * Dc))[tid] = o;

    float s = v.x * v.x + v.y * v.y + v.z * v.z + v.w * v.w;
    #pragma unroll
    for (int m = 1; m < 64; m <<= 1) s += __shfl_xor(s, m);
    __shared__ float ws[4];
    if ((tid & 63) == 0) ws[tid >> 6] = s;
    __syncthreads();
    if (tid == 0) {
        float t = ws[0] + ws[1] + ws[2] + ws[3];
        energy[row] = 1.0f / (1.0f + expf(-t));
    }
}

// ---------------- Kernel B: cast W1 -> bf16 ---------------------------------
__global__ void __launch_bounds__(256) cast_w1(
    const float* __restrict__ w1, unsigned short* __restrict__ w1b)
{
    const size_t i = (size_t)blockIdx.x * blockDim.x + threadIdx.x; // x4 elems
    const float4 v = ((const float4*)w1)[i];
    ushort4 o;
    o.x = f2bf(v.x); o.y = f2bf(v.y); o.z = f2bf(v.z); o.w = f2bf(v.w);
    ((ushort4*)w1b)[i] = o;
}

// ---------------- Kernel C: fused bf16 GEMM + relu + W2-reduce --------------
// 256x256 tile per block, 8 waves, double-buffered LDS, prefetch-1 staging,
// software-pipelined fragment reads (quadrant q+1 reads issued before
// quadrant q's MFMA cluster so the LDS pipe runs under the MFMA pipe).
// score_part[(ht*4 + wc)*Mc + row] = sum over slice's 64 h of
//     relu(x.W1[h] + b1[h]) * W2[h]
__global__ void __launch_bounds__(512, 2) fused_gemm_score(
    const unsigned short* __restrict__ xb,    // [Mc][Dc] bf16 bits
    const unsigned short* __restrict__ w1b,   // [Hc][Dc] bf16 bits
    const float* __restrict__ b1,             // [Hc]
    const float* __restrict__ w2,             // [Hc]
    float* __restrict__ score_part)           // [NSLICE][Mc]
{
    // dynamic LDS: [2 buf][2 mat][256*64] bf16 = 128 KB
    extern __shared__ __attribute__((aligned(16))) unsigned short lds[];

    const int tid  = threadIdx.x;
    const int lane = tid & 63;
    const int wid  = tid >> 6;                // 0..7
    const int wr   = wid >> 2;                // 0..1  (m half: 128 rows)
    const int wc   = wid & 3;                 // 0..3  (h quarter: 64 cols)
    const int l15  = lane & 15;
    const int l4   = lane >> 4;               // 0..3

    // bijective XCD swizzle (1024 % 8 == 0): ht fastest within an XCD so the
    // 8 blocks sharing one x-tile run adjacently; W1 (4MB) stays L2-resident.
    const int b  = blockIdx.x;
    const int wg = (b & 7) * (MTILES * HTILES / 8) + (b >> 3);
    const int mt = wg >> 3;                   // 0..127
    const int ht = wg & 7;                    // 0..7
    const int m0 = mt * BM;
    const int h0 = ht * BH;

    // epilogue coefficients prefetch
    float b1v[4], w2v[4];
    #pragma unroll
    for (int n = 0; n < 4; ++n) {
        const int h = h0 + wc * 64 + n * 16 + l15;
        b1v[n] = b1[h];
        w2v[n] = w2[h];
    }

    // staging geometry (rule #21: linear LDS dest + pre-swizzled src col)
    const int srow    = tid >> 3;             // 0..63
    const int scol_sw = ((((tid & 7) * 16) ^ ((srow & 7) << 4)) >> 1); // elems

    unsigned short* A0p = lds;                // [buf*32768 + mat*16384] elems
    #define LDSBUF(buf, mat) (A0p + (buf) * 32768 + (mat) * 16384)

    // swizzled ds_read byte offsets within a 128-byte row
    const int swz   = (l15 & 7) << 4;
    const int offk0 = ((l4 * 16) ^ swz);
    const int offk1 = ((64 + l4 * 16) ^ swz);
    const int arow  = (wr * 128 + l15) * 128; // byte row base within A
    const int brow  = (wc * 64 + l15) * 128;  // byte row base within B

// fragment reads (8 b128 for an A m-half, 4 b128 for a B n-half)
#define RD_A(dst, bf, mh) { \
    _Pragma("unroll") for (int mf = 0; mf < 4; ++mf) { \
        dst[mf][0] = *(const bf16x8*)((char*)LDSBUF(bf, 0) + arow + ((mh)*64 + mf*16) * 128 + offk0); \
        dst[mf][1] = *(const bf16x8*)((char*)LDSBUF(bf, 0) + arow + ((mh)*64 + mf*16) * 128 + offk1); } }
#define RD_B(dst, bf, nh) { \
    _Pragma("unroll") for (int nf = 0; nf < 2; ++nf) { \
        dst[nf][0] = *(const bf16x8*)((char*)LDSBUF(bf, 1) + brow + ((nh)*32 + nf*16) * 128 + offk0); \
        dst[nf][1] = *(const bf16x8*)((char*)LDSBUF(bf, 1) + brow + ((nh)*32 + nf*16) * 128 + offk1); } }

// one C-quadrant (m-half x n-half) x K=64 : 16 MFMA
#define MMQ(av, bv, mh, nh) { \
    __builtin_amdgcn_s_setprio(1); \
    _Pragma("unroll") for (int mf = 0; mf < 4; ++mf) \
    _Pragma("unroll") for (int nf = 0; nf < 2; ++nf) { \
        acc[(mh)*4+mf][(nh)*2+nf] = __builtin_amdgcn_mfma_f32_16x16x32_bf16( \
            av[mf][0], bv[nf][0], acc[(mh)*4+mf][(nh)*2+nf], 0, 0, 0); \
        acc[(mh)*4+mf][(nh)*2+nf] = __builtin_amdgcn_mfma_f32_16x16x32_bf16( \
            av[mf][1], bv[nf][1], acc[(mh)*4+mf][(nh)*2+nf], 0, 0, 0); } \
    __builtin_amdgcn_s_setprio(0); }

    f32x4 acc[8][4];
    #pragma unroll
    for (int m = 0; m < 8; ++m)
        #pragma unroll
        for (int n = 0; n < 4; ++n) acc[m][n] = (f32x4)(0.0f);

    // prologue: stage K-tile 0 into buf 0
    #pragma unroll
    for (int c = 0; c < 4; ++c) {
        stage16(xb  + (size_t)(m0 + c * 64 + srow) * Dc + scol_sw,
                ((char*)LDSBUF(0, 0)) + c * 8192 + tid * 16);
        stage16(w1b + (size_t)(h0 + c * 64 + srow) * Dc + scol_sw,
                ((char*)LDSBUF(0, 1)) + c * 8192 + tid * 16);
    }
    __syncthreads();   // compiler drains vmcnt(0) here

    int cur = 0;
    for (int kt = 0; kt < KTILES; ++kt) {
        // issue next-tile staging first: in flight across this tile's compute
        if (kt + 1 < KTILES) {
            const int k0 = (kt + 1) * BK;
            const int nb = cur ^ 1;
            #pragma unroll
            for (int c = 0; c < 4; ++c) {
                stage16(xb  + (size_t)(m0 + c * 64 + srow) * Dc + k0 + scol_sw,
                        ((char*)LDSBUF(nb, 0)) + c * 8192 + tid * 16);
                stage16(w1b + (size_t)(h0 + c * 64 + srow) * Dc + k0 + scol_sw,
                        ((char*)LDSBUF(nb, 1)) + c * 8192 + tid * 16);
            }
        }

        bf16x8 a0[4][2], a1[4][2], b0[2][2], b1f[2][2];

        // software pipeline: reads for quadrant q+1 issued BEFORE MFMA(q)
        RD_A(a0, cur, 0); RD_B(b0, cur, 0);   // q0 operands (8-read burst)
        RD_B(b1f, cur, 1);                    // q1 operand, under MM(q0)
        MMQ(a0, b0, 0, 0);                    // lgkmcnt(4): waits a0,b0 only
        RD_A(a1, cur, 1);                     // q2 operand, under MM(q1)
        MMQ(a0, b1f, 0, 1);                   // lgkmcnt(4): waits b1f only
        MMQ(a1, b1f, 1, 1);                   // lgkmcnt(0): waits a1
        MMQ(a1, b0, 1, 0);                    // all held in regs

        __syncthreads();   // next buffer staged; all reads of cur done
        cur ^= 1;
    }

    // fold: +b1, relu, *W2 -> per-row partials, then reduce over l15 columns
    float sp[8][4];
    #pragma unroll
    for (int m = 0; m < 8; ++m)
        #pragma unroll
        for (int j = 0; j < 4; ++j) sp[m][j] = 0.0f;
    #pragma unroll
    for (int n = 0; n < 4; ++n)
        #pragma unroll
        for (int m = 0; m < 8; ++m)
            #pragma unroll
            for (int j = 0; j < 4; ++j) {
                float v = acc[m][n][j] + b1v[n];
                v = v > 0.0f ? v : 0.0f;
                sp[m][j] += v * w2v[n];
            }

    #pragma unroll
    for (int m = 0; m < 8; ++m)
        #pragma unroll
        for (int j = 0; j < 4; ++j) {
            float v = sp[m][j];
            v += __shfl_xor(v, 1);
            v += __shfl_xor(v, 2);
            v += __shfl_xor(v, 4);
            v += __shfl_xor(v, 8);
            sp[m][j] = v;
        }

    if (l15 == 0) {
        const size_t base = (size_t)(ht * 4 + wc) * Mc;
        #pragma unroll
        for (int m = 0; m < 8; ++m)
            #pragma unroll
            for (int j = 0; j < 4; ++j) {
                const int row = m0 + wr * 128 + m * 16 + l4 * 4 + j;
                score_part[base + row] = sp[m][j];
            }
    }
}

// ---------------- Kernel D: finalize + write filter matrix ------------------
__global__ void __launch_bounds__(256) finalize(
    const float* __restrict__ score_part, const float* __restrict__ energy,
    const float* __restrict__ b2, float* __restrict__ out)
{
    const int row = blockIdx.x * 2 + (threadIdx.x >> 7);  // 0..Mc-1
    const int t   = threadIdx.x & 127;                    // 128 thr per row

    float s = b2[0];
    #pragma unroll
    for (int g = 0; g < NSLICE; ++g) s += score_part[(size_t)g * Mc + row];
    const float attn = (1.0f / (1.0f + expf(-s))) * energy[row];

    const int n = row & (Nc - 1);
    float4 z = make_float4(0.0f, 0.0f, 0.0f, 0.0f);
    if (t == (n >> 2)) ((float*)&z)[n & 3] = attn;
    ((float4*)(out + (size_t)row * Nc))[t] = z;
    if (t == 0) out[(size_t)Bc * Nc * Nc + row] = attn;
}

// ---------------- Host launcher ---------------------------------------------
extern "C" void kernel_launch(void* const* d_in, const int* in_sizes, int n_in,
                              void* d_out, int out_size, void* d_ws, size_t ws_size,
                              hipStream_t stream) {
    const float* x  = (const float*)d_in[0];
    const float* W1 = (const float*)d_in[1];
    const float* b1 = (const float*)d_in[2];
    const float* W2 = (const float*)d_in[3];
    const float* b2 = (const float*)d_in[4];
    float* out = (float*)d_out;

    const size_t xb_bytes = (size_t)Mc * Dc * 2;     // 64 MB
    const size_t w1_bytes = (size_t)Hc * Dc * 2;     // 4 MB
    const size_t e_bytes  = (size_t)Mc * 4;          // 128 KB
    const size_t s_bytes  = (size_t)NSLICE * Mc * 4; // 4 MB

    char* ws = (char*)d_ws;
    unsigned short* xb;
    if (ws_size >= xb_bytes + w1_bytes + e_bytes + s_bytes + 256) {
        xb = (unsigned short*)ws; ws += xb_bytes;
    } else {
        // use the filter region of d_out (67 MB >= 64 MB) as bf16-x scratch;
        // finalize() fully overwrites it afterwards.
        xb = (unsigned short*)d_out;
    }
    unsigned short* w1b = (unsigned short*)ws; ws += w1_bytes;
    float* energy = (float*)ws; ws += e_bytes;
    float* score  = (float*)ws; ws += s_bytes;

    cast_energy<<<Mc, 256, 0, stream>>>(x, xb, energy);
    cast_w1<<<(Hc * Dc / 4) / 256, 256, 0, stream>>>(W1, w1b);
    fused_gemm_score<<<MTILES * HTILES, 512, 131072, stream>>>(xb, w1b, b1, W2, score);
    finalize<<<Mc / 2, 256, 0, stream>>>(score, energy, b2, out);
}